// Round 4
// baseline (135.490 us; speedup 1.0000x reference)
//
#include <hip/hip_runtime.h>
#include <math.h>

// Sizes fixed by the reference problem.
#define Bn 32
#define Sn 8192
#define Dn 256
#define Cn 512                 // 2*D
#define NCHUNK 64              // S-chunks per batch
#define CHUNK (Sn / NCHUNK)    // 128 rows per block

// Workspace layout (float offsets). Total ~5.06 MiB.
#define WS_U     0                          // [512]  u[c] = sum_d va[d]*Ua[d,c]
#define WS_QV    512                        // [32]   qv[b] = input[b] . (Wa^T va)
#define WS_ALIGN 1024                       // [B*S]  raw align scores (-inf masked)
#define WS_PM    (WS_ALIGN + Bn * Sn)       // [B*NCHUNK] per-chunk running max
#define WS_PL    (WS_PM + Bn * NCHUNK)      // [B*NCHUNK] per-chunk exp-sum
#define WS_PACC  (WS_PL + Bn * NCHUNK)      // [B*NCHUNK*Cn] per-chunk weighted ctx
#define WS_UPART (WS_PACC + Bn * NCHUNK * Cn) // [16*Cn] u partials

// ---------------------------------------------------------------------------
// prep1: blocks 0..15 compute u-partials (16 Ua rows each, coalesced);
//        block 16 computes w[d] = sum_e va[e]*Wa[e,d] then qv[b] = input[b].w
__global__ void ga_prep1(const float* __restrict__ input,
                         const float* __restrict__ Wa,
                         const float* __restrict__ Ua,
                         const float* __restrict__ va,
                         float* __restrict__ ws) {
  const int tid = threadIdx.x;
  if (blockIdx.x < 16) {
    const int d0 = blockIdx.x * 16;
    float a0 = 0.f, a1 = 0.f;
#pragma unroll
    for (int j = 0; j < 16; ++j) {
      const float vd = va[d0 + j];
      const float* row = Ua + (size_t)(d0 + j) * Cn;
      a0 += vd * row[tid];
      a1 += vd * row[tid + 256];
    }
    ws[WS_UPART + blockIdx.x * Cn + tid] = a0;
    ws[WS_UPART + blockIdx.x * Cn + tid + 256] = a1;
  } else {
    __shared__ float wsh[Dn];
    float w = 0.f;
    for (int e = 0; e < Dn; ++e)
      w += va[e] * Wa[(size_t)e * Dn + tid];   // coalesced across tid
    wsh[tid] = w;
    __syncthreads();
    // qv: 8 threads per batch, reduce within wave
    const int b = tid >> 3, l8 = tid & 7;
    float p = 0.f;
#pragma unroll
    for (int j = 0; j < Dn / 8; ++j) {
      const int d = l8 + j * 8;
      p += input[b * Dn + d] * wsh[d];
    }
    p += __shfl_xor(p, 1);
    p += __shfl_xor(p, 2);
    p += __shfl_xor(p, 4);
    if (l8 == 0) ws[WS_QV + b] = p;
  }
}

// prep2: reduce the 16 u-partials -> u[512]
__global__ void ga_prep2(float* __restrict__ ws) {
  const int c = blockIdx.x * 256 + threadIdx.x;
  float s = 0.f;
#pragma unroll
  for (int i = 0; i < 16; ++i) s += ws[WS_UPART + i * Cn + c];
  ws[WS_U + c] = s;
}

// ---------------------------------------------------------------------------
// main: one block per (b, chunk of 128 rows). 4 waves, one row per wave per
// iteration. Each lane owns 8 u-columns; the two float4 context loads feed
// BOTH the score dot-product and the online-softmax-weighted accumulation,
// so context is read from HBM exactly once.
__global__ __launch_bounds__(256) void ga_main(const float* __restrict__ context,
                                               const int* __restrict__ lens,
                                               float* __restrict__ ws) {
  const int b   = blockIdx.x >> 6;   // NCHUNK = 64
  const int ic  = blockIdx.x & 63;
  const int tid  = threadIdx.x;
  const int wave = tid >> 6;
  const int lane = tid & 63;
  const int len = lens[b];
  const float qv = ws[WS_QV + b];

  const float4* uv = (const float4*)(ws + WS_U);
  const float4 u0 = uv[lane];
  const float4 u1 = uv[64 + lane];

  float m = -INFINITY, l = 0.f;
  float4 a0 = make_float4(0.f, 0.f, 0.f, 0.f);
  float4 a1 = make_float4(0.f, 0.f, 0.f, 0.f);

  const int s0 = ic * CHUNK;
  float* alout = ws + WS_ALIGN + (size_t)b * Sn;

  for (int it = 0; it < CHUNK / 4; ++it) {
    const int s = s0 + it * 4 + wave;
    const float4* ctx = (const float4*)(context + ((size_t)b * Sn + s) * Cn);
    const float4 f0 = ctx[lane];        // cols [4*lane, 4*lane+4)
    const float4 f1 = ctx[64 + lane];   // cols [256+4*lane, ...)

    float dot = f0.x * u0.x + f0.y * u0.y + f0.z * u0.z + f0.w * u0.w
              + f1.x * u1.x + f1.y * u1.y + f1.z * u1.z + f1.w * u1.w;
#pragma unroll
    for (int off = 32; off; off >>= 1) dot += __shfl_xor(dot, off);

    const float al = qv + dot;
    const bool valid = (s < len);       // wave-uniform, no divergence
    if (lane == 0) alout[s] = valid ? al : -INFINITY;

    if (valid) {
      const float mn = fmaxf(m, al);
      const float sc = __expf(m - mn);  // m=-inf first time -> sc=0, safe
      const float p  = __expf(al - mn);
      l = l * sc + p;
      a0.x = a0.x * sc + p * f0.x;  a0.y = a0.y * sc + p * f0.y;
      a0.z = a0.z * sc + p * f0.z;  a0.w = a0.w * sc + p * f0.w;
      a1.x = a1.x * sc + p * f1.x;  a1.y = a1.y * sc + p * f1.y;
      a1.z = a1.z * sc + p * f1.z;  a1.w = a1.w * sc + p * f1.w;
      m = mn;
    }
  }

  // combine the 4 waves' online states -> one block partial
  __shared__ float msh[4], lsh[4];
  __shared__ float accsh[4][Cn];
  if (lane == 0) msh[wave] = m;
  __syncthreads();
  const float M = fmaxf(fmaxf(msh[0], msh[1]), fmaxf(msh[2], msh[3]));
  const float f = (m == -INFINITY) ? 0.f : __expf(m - M);  // guard NaN when M=-inf
  float4* arow = (float4*)accsh[wave];
  arow[lane]      = make_float4(a0.x * f, a0.y * f, a0.z * f, a0.w * f);
  arow[64 + lane] = make_float4(a1.x * f, a1.y * f, a1.z * f, a1.w * f);
  if (lane == 0) lsh[wave] = l * f;
  __syncthreads();

  const int idx = blockIdx.x;            // == b*NCHUNK + ic
  float* pacc = ws + WS_PACC + (size_t)idx * Cn;
  for (int ch = tid; ch < Cn; ch += 256)
    pacc[ch] = accsh[0][ch] + accsh[1][ch] + accsh[2][ch] + accsh[3][ch];
  if (tid == 0) {
    ws[WS_PM + idx] = M;
    ws[WS_PL + idx] = lsh[0] + lsh[1] + lsh[2] + lsh[3];
  }
}

// ---------------------------------------------------------------------------
// finalize: per batch, combine 64 chunk partials (global M, L), write
// attn_h = sum_i w_i*acc_i / L and align_vectors = exp(align - M)/L.
__global__ void ga_finalize(const float* __restrict__ ws, float* __restrict__ out) {
  const int b = blockIdx.x;
  const int tid = threadIdx.x;
  __shared__ float wgt[NCHUNK];
  __shared__ float Msh, Lish;

  if (tid < NCHUNK) {                    // NCHUNK==64 -> exactly wave 0
    const float mi = ws[WS_PM + b * NCHUNK + tid];
    float mm = mi;
#pragma unroll
    for (int off = 32; off; off >>= 1) mm = fmaxf(mm, __shfl_xor(mm, off));
    const float wi = (mi == -INFINITY) ? 0.f : __expf(mi - mm);
    wgt[tid] = wi;
    float li = ws[WS_PL + b * NCHUNK + tid] * wi;
#pragma unroll
    for (int off = 32; off; off >>= 1) li += __shfl_xor(li, off);
    if (tid == 0) { Msh = mm; Lish = 1.f / li; }
  }
  __syncthreads();
  const float M = Msh, Li = Lish;

  // attn_h: [B, 2D] at out[0 .. B*Cn)
  const float* pacc = ws + WS_PACC + (size_t)b * NCHUNK * Cn;
  const int c0 = tid, c1 = tid + 256;
  float s0 = 0.f, s1 = 0.f;
  for (int i = 0; i < NCHUNK; ++i) {
    const float w = wgt[i];
    s0 += w * pacc[i * Cn + c0];
    s1 += w * pacc[i * Cn + c1];
  }
  out[b * Cn + c0] = s0 * Li;
  out[b * Cn + c1] = s1 * Li;

  // align_vectors: [B, S] at out[B*Cn ...)
  const float* al = ws + WS_ALIGN + (size_t)b * Sn;
  float* ao = out + Bn * Cn + (size_t)b * Sn;
  for (int s = tid; s < Sn; s += 256)
    ao[s] = __expf(al[s] - M) * Li;      // exp(-inf - M) == 0 for masked
}

// ---------------------------------------------------------------------------
extern "C" void kernel_launch(void* const* d_in, const int* in_sizes, int n_in,
                              void* d_out, int out_size, void* d_ws, size_t ws_size,
                              hipStream_t stream) {
  const float* input   = (const float*)d_in[0];
  const float* context = (const float*)d_in[1];
  const float* Wa      = (const float*)d_in[2];
  const float* Ua      = (const float*)d_in[3];
  const float* va      = (const float*)d_in[4];
  const int*   lens    = (const int*)d_in[5];
  float* out = (float*)d_out;
  float* ws  = (float*)d_ws;

  ga_prep1<<<17, 256, 0, stream>>>(input, Wa, Ua, va, ws);
  ga_prep2<<<2, 256, 0, stream>>>(ws);
  ga_main<<<Bn * NCHUNK, 256, 0, stream>>>(context, lens, ws);
  ga_finalize<<<Bn, 256, 0, stream>>>(ws, out);
}

// Round 5
// 122.079 us; speedup vs baseline: 1.1099x; 1.1099x over previous
//
#include <hip/hip_runtime.h>
#include <math.h>

// Sizes fixed by the reference problem.
#define Bn 32
#define Sn 8192
#define Dn 256
#define Cn 512                 // 2*D
#define NCHUNK 64              // chunks (blocks) per batch

// Workspace layout (float offsets). ~5.02 MiB total.
#define WS_U     0                          // [512]  u[c] = sum_d va[d]*Ua[d,c]
#define WS_QV    512                        // [32]   qv[b] = input[b] . (Wa^T va)
#define WS_PM    544                        // [B*NCHUNK] per-chunk running max
#define WS_PL    (WS_PM + Bn * NCHUNK)      // [B*NCHUNK] per-chunk exp-sum
#define WS_ALIGN (WS_PL + Bn * NCHUNK)      // [B*S] raw align (valid rows only)
#define WS_PACC  (WS_ALIGN + Bn * Sn)       // [B*NCHUNK*Cn] per-chunk weighted ctx
// prep partials overlay PACC (consumed before ga_main writes PACC):
#define WS_UPART WS_PACC                    // [64*Cn]
#define WS_WPART (WS_PACC + 64 * Cn)        // [4*Dn]

// ---------------------------------------------------------------------------
// prep1: blocks 0..63  -> u-partials (4 Ua rows each, coalesced)
//        blocks 64..67 -> w-partials (64 Wa rows each): w[d] = sum_e va[e]Wa[e,d]
__global__ void ga_prep1(const float* __restrict__ Wa,
                         const float* __restrict__ Ua,
                         const float* __restrict__ va,
                         float* __restrict__ ws) {
  const int tid = threadIdx.x, bx = blockIdx.x;
  if (bx < 64) {
    const int d0 = bx * 4;
    float a0 = 0.f, a1 = 0.f;
#pragma unroll
    for (int j = 0; j < 4; ++j) {
      const float vd = va[d0 + j];
      const float* row = Ua + (size_t)(d0 + j) * Cn;
      a0 += vd * row[tid];
      a1 += vd * row[tid + 256];
    }
    ws[WS_UPART + bx * Cn + tid] = a0;
    ws[WS_UPART + bx * Cn + tid + 256] = a1;
  } else {
    const int k = bx - 64;                  // 0..3, rows [64k, 64k+64)
    float wacc = 0.f;
    for (int e = k * 64; e < k * 64 + 64; ++e)
      wacc += va[e] * Wa[(size_t)e * Dn + tid];   // coalesced across tid
    ws[WS_WPART + k * Dn + tid] = wacc;
  }
}

// prep2: blocks 0,1 reduce u-partials -> u[512]; block 2 reduces w, then qv[b]
__global__ void ga_prep2(const float* __restrict__ input, float* __restrict__ ws) {
  const int tid = threadIdx.x, bx = blockIdx.x;
  if (bx < 2) {
    const int c = bx * 256 + tid;
    float s = 0.f;
#pragma unroll
    for (int i = 0; i < 64; ++i) s += ws[WS_UPART + i * Cn + c];
    ws[WS_U + c] = s;
  } else {
    __shared__ float wsh[Dn];
    wsh[tid] = ws[WS_WPART + tid] + ws[WS_WPART + 256 + tid]
             + ws[WS_WPART + 512 + tid] + ws[WS_WPART + 768 + tid];
    __syncthreads();
    const int b = tid >> 3, l8 = tid & 7;   // 8 threads per batch
    float p = 0.f;
#pragma unroll
    for (int j = 0; j < Dn / 8; ++j) {
      const int d = l8 + j * 8;
      p += input[b * Dn + d] * wsh[d];
    }
    p += __shfl_xor(p, 1);
    p += __shfl_xor(p, 2);
    p += __shfl_xor(p, 4);
    if (l8 == 0) ws[WS_QV + b] = p;
  }
}

// ---------------------------------------------------------------------------
// main: one block per (b, chunk). Only VALID rows (s < len) are partitioned
// across the 64 chunks, so masked context rows are never fetched from HBM.
// 4 waves, one row per wave per iteration; the two float4 loads feed BOTH the
// score dot (butterfly reduce) and the online-softmax weighted accumulation.
// b = blockIdx&31 interleaves batches across consecutive blocks for balance.
__global__ __launch_bounds__(256) void ga_main(const float* __restrict__ context,
                                               const int* __restrict__ lens,
                                               float* __restrict__ ws) {
  const int b   = blockIdx.x & 31;
  const int ic  = blockIdx.x >> 5;
  const int tid  = threadIdx.x;
  const int wave = tid >> 6;
  const int lane = tid & 63;
  const int len = lens[b];
  const int NIT = (len + 3) >> 2;          // 4-row iterations covering [0,len)
  const int it0 = (ic * NIT) >> 6;         // this chunk's iteration range
  const int it1 = ((ic + 1) * NIT) >> 6;
  const float qv = ws[WS_QV + b];

  const float4* uv = (const float4*)(ws + WS_U);
  const float4 u0 = uv[lane];
  const float4 u1 = uv[64 + lane];

  float m = -INFINITY, l = 0.f;
  float4 a0 = make_float4(0.f, 0.f, 0.f, 0.f);
  float4 a1 = make_float4(0.f, 0.f, 0.f, 0.f);
  float* alout = ws + WS_ALIGN + (size_t)b * Sn;

  for (int it = it0; it < it1; ++it) {
    const int s = it * 4 + wave;           // s <= 4*NIT-1 <= 8191: always in-bounds
    const float4* ctx = (const float4*)(context + ((size_t)b * Sn + s) * Cn);
    const float4 f0 = ctx[lane];           // cols [4*lane, 4*lane+4)
    const float4 f1 = ctx[64 + lane];      // cols [256+4*lane, ...)

    float dot = f0.x * u0.x + f0.y * u0.y + f0.z * u0.z + f0.w * u0.w
              + f1.x * u1.x + f1.y * u1.y + f1.z * u1.z + f1.w * u1.w;
#pragma unroll
    for (int off = 32; off; off >>= 1) dot += __shfl_xor(dot, off);

    if (s < len) {                         // only tail-iteration waves fail this
      const float al = qv + dot;
      if (lane == 0) alout[s] = al;
      const float mn = fmaxf(m, al);
      const float sc = __expf(m - mn);     // m=-inf first time -> sc=0, safe
      const float p  = __expf(al - mn);
      l = l * sc + p;
      a0.x = a0.x * sc + p * f0.x;  a0.y = a0.y * sc + p * f0.y;
      a0.z = a0.z * sc + p * f0.z;  a0.w = a0.w * sc + p * f0.w;
      a1.x = a1.x * sc + p * f1.x;  a1.y = a1.y * sc + p * f1.y;
      a1.z = a1.z * sc + p * f1.z;  a1.w = a1.w * sc + p * f1.w;
      m = mn;
    }
  }

  // combine the 4 waves' online states -> one block partial
  __shared__ float msh[4], lsh[4];
  __shared__ float accsh[4][Cn];
  if (lane == 0) msh[wave] = m;
  __syncthreads();
  const float M = fmaxf(fmaxf(msh[0], msh[1]), fmaxf(msh[2], msh[3]));
  const float f = (m == -INFINITY) ? 0.f : __expf(m - M);  // guard NaN
  float4* arow = (float4*)accsh[wave];
  arow[lane]      = make_float4(a0.x * f, a0.y * f, a0.z * f, a0.w * f);
  arow[64 + lane] = make_float4(a1.x * f, a1.y * f, a1.z * f, a1.w * f);
  if (lane == 0) lsh[wave] = l * f;
  __syncthreads();

  const int idx = b * NCHUNK + ic;
  float* pacc = ws + WS_PACC + (size_t)idx * Cn;
  for (int ch = tid; ch < Cn; ch += 256)
    pacc[ch] = accsh[0][ch] + accsh[1][ch] + accsh[2][ch] + accsh[3][ch];
  if (tid == 0) {
    ws[WS_PM + idx] = M;
    ws[WS_PL + idx] = lsh[0] + lsh[1] + lsh[2] + lsh[3];
  }
}

// ---------------------------------------------------------------------------
// finalize: 8 blocks per batch. Each recomputes (M, 1/L, wgt[64]) from the
// tiny per-chunk partials, then handles 64 channels of attn_h and 1024
// positions of align_vectors.
__global__ __launch_bounds__(256) void ga_finalize(const float* __restrict__ ws,
                                                   const int* __restrict__ lens,
                                                   float* __restrict__ out) {
  const int b = blockIdx.x >> 3, p = blockIdx.x & 7;
  const int tid = threadIdx.x;
  __shared__ float wgt[NCHUNK];
  __shared__ float red[4][64];
  __shared__ float Msh, Lish;

  if (tid < NCHUNK) {                      // exactly wave 0
    const float mi = ws[WS_PM + b * NCHUNK + tid];
    float mm = mi;
#pragma unroll
    for (int off = 32; off; off >>= 1) mm = fmaxf(mm, __shfl_xor(mm, off));
    const float wi = (mi == -INFINITY) ? 0.f : __expf(mi - mm);
    wgt[tid] = wi;
    float li = ws[WS_PL + b * NCHUNK + tid] * wi;
#pragma unroll
    for (int off = 32; off; off >>= 1) li += __shfl_xor(li, off);
    if (tid == 0) { Msh = mm; Lish = 1.f / li; }
  }
  __syncthreads();
  const float M = Msh, Li = Lish;

  // attn_h: this block covers channels [64p, 64p+64)
  {
    const int c = p * 64 + (tid & 63), g = tid >> 6;
    const float* pacc = ws + WS_PACC + (size_t)b * NCHUNK * Cn;
    float s = 0.f;
    for (int i = g; i < NCHUNK; i += 4) s += wgt[i] * pacc[i * Cn + c];
    red[g][tid & 63] = s;
    __syncthreads();
    if (tid < 64)
      out[b * Cn + p * 64 + tid] =
          (red[0][tid] + red[1][tid] + red[2][tid] + red[3][tid]) * Li;
  }

  // align_vectors: this block covers s in [1024p, 1024p+1024)
  {
    const int len = lens[b];
    const float* al = ws + WS_ALIGN + (size_t)b * Sn;
    float* ao = out + Bn * Cn + (size_t)b * Sn;
    const int s0 = p * 1024 + tid * 4;
    const float4 v = *(const float4*)(al + s0);  // s>=len lanes read garbage,
    float4 o;                                    // discarded by the selects:
    o.x = (s0 + 0 < len) ? __expf(v.x - M) * Li : 0.f;
    o.y = (s0 + 1 < len) ? __expf(v.y - M) * Li : 0.f;
    o.z = (s0 + 2 < len) ? __expf(v.z - M) * Li : 0.f;
    o.w = (s0 + 3 < len) ? __expf(v.w - M) * Li : 0.f;
    *(float4*)(ao + s0) = o;
  }
}

// ---------------------------------------------------------------------------
extern "C" void kernel_launch(void* const* d_in, const int* in_sizes, int n_in,
                              void* d_out, int out_size, void* d_ws, size_t ws_size,
                              hipStream_t stream) {
  const float* input   = (const float*)d_in[0];
  const float* context = (const float*)d_in[1];
  const float* Wa      = (const float*)d_in[2];
  const float* Ua      = (const float*)d_in[3];
  const float* va      = (const float*)d_in[4];
  const int*   lens    = (const int*)d_in[5];
  float* out = (float*)d_out;
  float* ws  = (float*)d_ws;

  ga_prep1<<<68, 256, 0, stream>>>(Wa, Ua, va, ws);
  ga_prep2<<<3, 256, 0, stream>>>(input, ws);
  ga_main<<<Bn * NCHUNK, 256, 0, stream>>>(context, lens, ws);
  ga_finalize<<<Bn * 8, 256, 0, stream>>>(ws, lens, out);
}

// Round 6
// 119.671 us; speedup vs baseline: 1.1322x; 1.0201x over previous
//
#include <hip/hip_runtime.h>
#include <math.h>

// Sizes fixed by the reference problem.
#define Bn 32
#define Sn 8192
#define Dn 256
#define Cn 512                 // 2*D
#define NBLK 2048              // ga_main grid = exactly 8 blocks/CU x 256 CUs

// Workspace layout (float offsets). ~5.3 MiB total.
#define WS_U     0                          // [512]  u[c] = sum_d va[d]*Ua[d,c]
#define WS_QV    512                        // [32]   qv[b] = input[b] . (Wa^T va)
#define WS_PM    544                        // [NBLK] per-block running max
#define WS_PL    (WS_PM + NBLK)             // [NBLK] per-block exp-sum
#define WS_ALIGN (WS_PL + NBLK)             // [B*S] raw align (valid rows only)
#define WS_PACC  (WS_ALIGN + Bn * Sn)       // [NBLK*Cn] per-block weighted ctx
// prep partials overlay PACC (consumed by prep2 before ga_main writes PACC):
#define WS_UPART WS_PACC                    // [64*Cn]
#define WS_WPART (WS_PACC + 64 * Cn)        // [4*Dn]

// ---------------------------------------------------------------------------
// Length-proportional partition of the global valid-iteration space.
// NIT_b = ceil(len_b/4) 4-row iterations per batch; batch b owns block range
// [f(P_b), f(P_b+NIT_b)) where f(P) = P*NBLK/TOT (int floor). Telescoping
// guarantees the ranges exactly tile [0, NBLK). Within a batch, block j of
// cnt covers iterations [j*NIT/cnt, (j+1)*NIT/cnt) -- same telescoping.
// All int32: P*NBLK <= 65536*2048 < 2^31.
__device__ inline void ga_partition(const int* __restrict__ lens, int k,
                                    int& b, int& it0, int& it1) {
  int TOT = 0;
#pragma unroll
  for (int i = 0; i < Bn; ++i) TOT += (lens[i] + 3) >> 2;
  int P = 0, bb = 0, offb = 0, cntb = 1, nitb = 1;
#pragma unroll
  for (int i = 0; i < Bn; ++i) {
    const int nit = (lens[i] + 3) >> 2;
    const int o0 = (P * NBLK) / TOT;
    const int o1 = ((P + nit) * NBLK) / TOT;
    if (k >= o0 && k < o1) { bb = i; offb = o0; cntb = o1 - o0; nitb = nit; }
    P += nit;
  }
  const int j = k - offb;
  b = bb;
  it0 = (j * nitb) / cntb;
  it1 = ((j + 1) * nitb) / cntb;
}

// Batch b's block range [offb, offb+cntb). cntb <= nit*NBLK/TOT + 1 <= ~130
// (lens >= S/2 => TOT >= 33792), so cntb < 256 always.
__device__ inline void ga_batch_range(const int* __restrict__ lens, int b,
                                      int& offb, int& cntb) {
  int TOT = 0;
#pragma unroll
  for (int i = 0; i < Bn; ++i) TOT += (lens[i] + 3) >> 2;
  int P = 0;
  for (int i = 0; i < b; ++i) P += (lens[i] + 3) >> 2;
  const int nit = (lens[b] + 3) >> 2;
  offb = (P * NBLK) / TOT;
  cntb = ((P + nit) * NBLK) / TOT - offb;
}

// ---------------------------------------------------------------------------
// prep1: blocks 0..63  -> u-partials (4 Ua rows each, coalesced)
//        blocks 64..67 -> w-partials (64 Wa rows each): w[d] = sum_e va[e]Wa[e,d]
__global__ void ga_prep1(const float* __restrict__ Wa,
                         const float* __restrict__ Ua,
                         const float* __restrict__ va,
                         float* __restrict__ ws) {
  const int tid = threadIdx.x, bx = blockIdx.x;
  if (bx < 64) {
    const int d0 = bx * 4;
    float a0 = 0.f, a1 = 0.f;
#pragma unroll
    for (int j = 0; j < 4; ++j) {
      const float vd = va[d0 + j];
      const float* row = Ua + (size_t)(d0 + j) * Cn;
      a0 += vd * row[tid];
      a1 += vd * row[tid + 256];
    }
    ws[WS_UPART + bx * Cn + tid] = a0;
    ws[WS_UPART + bx * Cn + tid + 256] = a1;
  } else {
    const int k = bx - 64;                  // rows [64k, 64k+64)
    float wacc = 0.f;
    for (int e = k * 64; e < k * 64 + 64; ++e)
      wacc += va[e] * Wa[(size_t)e * Dn + tid];   // coalesced across tid
    ws[WS_WPART + k * Dn + tid] = wacc;
  }
}

// prep2: blocks 0,1 reduce u-partials -> u[512]; block 2 reduces w, then qv[b]
__global__ void ga_prep2(const float* __restrict__ input, float* __restrict__ ws) {
  const int tid = threadIdx.x, bx = blockIdx.x;
  if (bx < 2) {
    const int c = bx * 256 + tid;
    float s = 0.f;
#pragma unroll
    for (int i = 0; i < 64; ++i) s += ws[WS_UPART + i * Cn + c];
    ws[WS_U + c] = s;
  } else {
    __shared__ float wsh[Dn];
    wsh[tid] = ws[WS_WPART + tid] + ws[WS_WPART + 256 + tid]
             + ws[WS_WPART + 512 + tid] + ws[WS_WPART + 768 + tid];
    __syncthreads();
    const int b = tid >> 3, l8 = tid & 7;   // 8 threads per batch
    float p = 0.f;
#pragma unroll
    for (int j = 0; j < Dn / 8; ++j) {
      const int d = l8 + j * 8;
      p += input[b * Dn + d] * wsh[d];
    }
    p += __shfl_xor(p, 1);
    p += __shfl_xor(p, 2);
    p += __shfl_xor(p, 4);
    if (l8 == 0) ws[WS_QV + b] = p;
  }
}

// ---------------------------------------------------------------------------
// main: NBLK blocks, work balanced by ga_partition (each block ~TOT/NBLK
// iterations). 4 waves, one row per wave per iteration; the two float4 loads
// feed BOTH the score dot (butterfly reduce) and the online-softmax weighted
// accumulation, so each valid context row is fetched from HBM exactly once.
// __launch_bounds__(256, 8): cap VGPR at 64 so all 2048 blocks are
// co-resident (8 blocks/CU, 32 waves/CU) -- no straggler rounds.
__global__ __launch_bounds__(256, 8) void ga_main(const float* __restrict__ context,
                                                  const int* __restrict__ lens,
                                                  float* __restrict__ ws) {
  const int k = blockIdx.x;
  int b, it0, it1;
  ga_partition(lens, k, b, it0, it1);
  const int tid  = threadIdx.x;
  const int wave = tid >> 6;
  const int lane = tid & 63;
  const int len = lens[b];
  const float qv = ws[WS_QV + b];

  const float4* uv = (const float4*)(ws + WS_U);
  const float4 u0 = uv[lane];
  const float4 u1 = uv[64 + lane];

  float m = -INFINITY, l = 0.f;
  float4 a0 = make_float4(0.f, 0.f, 0.f, 0.f);
  float4 a1 = make_float4(0.f, 0.f, 0.f, 0.f);
  float* alout = ws + WS_ALIGN + (size_t)b * Sn;

  for (int it = it0; it < it1; ++it) {
    const int s = it * 4 + wave;           // s <= 4*NIT-1 <= Sn-1: in-bounds
    const float4* ctx = (const float4*)(context + ((size_t)b * Sn + s) * Cn);
    const float4 f0 = ctx[lane];           // cols [4*lane, 4*lane+4)
    const float4 f1 = ctx[64 + lane];      // cols [256+4*lane, ...)

    float dot = f0.x * u0.x + f0.y * u0.y + f0.z * u0.z + f0.w * u0.w
              + f1.x * u1.x + f1.y * u1.y + f1.z * u1.z + f1.w * u1.w;
#pragma unroll
    for (int off = 32; off; off >>= 1) dot += __shfl_xor(dot, off);

    if (s < len) {                         // only tail-iteration waves fail
      const float al = qv + dot;
      if (lane == 0) alout[s] = al;
      const float mn = fmaxf(m, al);
      const float sc = __expf(m - mn);     // m=-inf first time -> sc=0, safe
      const float p  = __expf(al - mn);
      l = l * sc + p;
      a0.x = a0.x * sc + p * f0.x;  a0.y = a0.y * sc + p * f0.y;
      a0.z = a0.z * sc + p * f0.z;  a0.w = a0.w * sc + p * f0.w;
      a1.x = a1.x * sc + p * f1.x;  a1.y = a1.y * sc + p * f1.y;
      a1.z = a1.z * sc + p * f1.z;  a1.w = a1.w * sc + p * f1.w;
      m = mn;
    }
  }

  // combine the 4 waves' online states -> one block partial at index k
  __shared__ float msh[4], lsh[4];
  __shared__ float accsh[4][Cn];
  if (lane == 0) msh[wave] = m;
  __syncthreads();
  const float M = fmaxf(fmaxf(msh[0], msh[1]), fmaxf(msh[2], msh[3]));
  const float f = (m == -INFINITY) ? 0.f : __expf(m - M);  // guard NaN
  float4* arow = (float4*)accsh[wave];
  arow[lane]      = make_float4(a0.x * f, a0.y * f, a0.z * f, a0.w * f);
  arow[64 + lane] = make_float4(a1.x * f, a1.y * f, a1.z * f, a1.w * f);
  if (lane == 0) lsh[wave] = l * f;
  __syncthreads();

  float* pacc = ws + WS_PACC + (size_t)k * Cn;
  for (int ch = tid; ch < Cn; ch += 256)
    pacc[ch] = accsh[0][ch] + accsh[1][ch] + accsh[2][ch] + accsh[3][ch];
  if (tid == 0) {
    ws[WS_PM + k] = M;
    ws[WS_PL + k] = lsh[0] + lsh[1] + lsh[2] + lsh[3];
  }
}

// ---------------------------------------------------------------------------
// finalize: 8 blocks per batch. Each recomputes its batch's block range,
// reduces (M, 1/L, wgt[cnt]) from the tiny per-block partials, then handles
// 64 channels of attn_h and 1024 positions of align_vectors.
__global__ __launch_bounds__(256) void ga_finalize(const float* __restrict__ ws,
                                                   const int* __restrict__ lens,
                                                   float* __restrict__ out) {
  const int b = blockIdx.x >> 3, p = blockIdx.x & 7;
  const int tid = threadIdx.x;
  int offb, cntb;                          // cntb < 256 (see ga_batch_range)
  ga_batch_range(lens, b, offb, cntb);

  __shared__ float wgt[256];
  __shared__ float mred[4], lred[4];
  __shared__ float red[4][64];

  // block-wide max over cntb partial maxima
  const float mi = (tid < cntb) ? ws[WS_PM + offb + tid] : -INFINITY;
  float mm = mi;
#pragma unroll
  for (int off = 32; off; off >>= 1) mm = fmaxf(mm, __shfl_xor(mm, off));
  if ((tid & 63) == 0) mred[tid >> 6] = mm;
  __syncthreads();
  const float M = fmaxf(fmaxf(mred[0], mred[1]), fmaxf(mred[2], mred[3]));
  const float wi = (mi == -INFINITY) ? 0.f : __expf(mi - M);
  wgt[tid] = wi;
  float li = (tid < cntb) ? ws[WS_PL + offb + tid] * wi : 0.f;
#pragma unroll
  for (int off = 32; off; off >>= 1) li += __shfl_xor(li, off);
  if ((tid & 63) == 0) lred[tid >> 6] = li;
  __syncthreads();
  const float Li = 1.f / (lred[0] + lred[1] + lred[2] + lred[3]);

  // attn_h: this block covers channels [64p, 64p+64)
  {
    const int c = p * 64 + (tid & 63), g = tid >> 6;
    const float* pacc = ws + WS_PACC + (size_t)offb * Cn;
    float s = 0.f;
    for (int i = g; i < cntb; i += 4) s += wgt[i] * pacc[(size_t)i * Cn + c];
    red[g][tid & 63] = s;
    __syncthreads();
    if (tid < 64)
      out[b * Cn + p * 64 + tid] =
          (red[0][tid] + red[1][tid] + red[2][tid] + red[3][tid]) * Li;
  }

  // align_vectors: this block covers s in [1024p, 1024p+1024)
  {
    const int len = lens[b];
    const float* al = ws + WS_ALIGN + (size_t)b * Sn;
    float* ao = out + Bn * Cn + (size_t)b * Sn;
    const int s0 = p * 1024 + tid * 4;
    const float4 v = *(const float4*)(al + s0);  // s>=len lanes read stale ws,
    float4 o;                                    // discarded by the selects:
    o.x = (s0 + 0 < len) ? __expf(v.x - M) * Li : 0.f;
    o.y = (s0 + 1 < len) ? __expf(v.y - M) * Li : 0.f;
    o.z = (s0 + 2 < len) ? __expf(v.z - M) * Li : 0.f;
    o.w = (s0 + 3 < len) ? __expf(v.w - M) * Li : 0.f;
    *(float4*)(ao + s0) = o;
  }
}

// ---------------------------------------------------------------------------
extern "C" void kernel_launch(void* const* d_in, const int* in_sizes, int n_in,
                              void* d_out, int out_size, void* d_ws, size_t ws_size,
                              hipStream_t stream) {
  const float* input   = (const float*)d_in[0];
  const float* context = (const float*)d_in[1];
  const float* Wa      = (const float*)d_in[2];
  const float* Ua      = (const float*)d_in[3];
  const float* va      = (const float*)d_in[4];
  const int*   lens    = (const int*)d_in[5];
  float* out = (float*)d_out;
  float* ws  = (float*)d_ws;

  ga_prep1<<<68, 256, 0, stream>>>(Wa, Ua, va, ws);
  ga_prep2<<<3, 256, 0, stream>>>(input, ws);
  ga_main<<<NBLK, 256, 0, stream>>>(context, lens, ws);
  ga_finalize<<<Bn * 8, 256, 0, stream>>>(ws, lens, out);
}

// Round 7
// 111.305 us; speedup vs baseline: 1.2173x; 1.0752x over previous
//
#include <hip/hip_runtime.h>
#include <math.h>

// Sizes fixed by the reference problem.
#define Bn 32
#define Sn 8192
#define Dn 256
#define Cn 512                 // 2*D
#define NBLK 1024              // ga_main grid = exactly 4 blocks/CU x 256 CUs

// Workspace layout (float offsets). ~3.2 MiB total.
#define WS_U     0                          // [512]  u[c] = sum_d va[d]*Ua[d,c]
#define WS_QV    512                        // [32]   qv[b] = input[b] . (Wa^T va)
#define WS_PM    544                        // [NBLK] per-block running max
#define WS_PL    (WS_PM + NBLK)             // [NBLK] per-block exp-sum
#define WS_PLAN  (WS_PL + NBLK)             // [NBLK] packed (b,it0,it1) ints
#define WS_ALIGN (WS_PLAN + NBLK)           // [B*S] raw align (valid rows only)
#define WS_PACC  (WS_ALIGN + Bn * Sn)       // [NBLK*Cn] per-block weighted ctx
// prep partials overlay PACC (consumed by prep2 before ga_main writes PACC):
#define WS_UPART WS_PACC                    // [64*Cn]
#define WS_WPART (WS_PACC + 64 * Cn)        // [4*Dn]

// ---------------------------------------------------------------------------
// Length-proportional partition of the global valid-iteration space.
// NIT_b = ceil(len_b/4); batch b owns block range [f(P_b), f(P_b+NIT_b)),
// f(P) = P*NBLK/TOT (floor). Telescoping => ranges exactly tile [0,NBLK).
// Within a batch, block j of cnt covers iterations [j*NIT/cnt,(j+1)*NIT/cnt).
// cnt <= NIT*NBLK/TOT + 1 <= 63 (lens >= S/2 => TOT >= 33792), and
// cnt <= NIT so every block gets >= 1 iteration. All int32 safe.
__device__ inline void ga_partition(const int* __restrict__ lens, int k,
                                    int& b, int& it0, int& it1) {
  int TOT = 0;
#pragma unroll
  for (int i = 0; i < Bn; ++i) TOT += (lens[i] + 3) >> 2;
  int P = 0, bb = 0, offb = 0, cntb = 1, nitb = 1;
#pragma unroll
  for (int i = 0; i < Bn; ++i) {
    const int nit = (lens[i] + 3) >> 2;
    const int o0 = (P * NBLK) / TOT;
    const int o1 = ((P + nit) * NBLK) / TOT;
    if (k >= o0 && k < o1) { bb = i; offb = o0; cntb = o1 - o0; nitb = nit; }
    P += nit;
  }
  const int j = k - offb;
  b = bb;
  it0 = (j * nitb) / cntb;
  it1 = ((j + 1) * nitb) / cntb;
}

__device__ inline void ga_batch_range(const int* __restrict__ lens, int b,
                                      int& offb, int& cntb) {
  int TOT = 0;
#pragma unroll
  for (int i = 0; i < Bn; ++i) TOT += (lens[i] + 3) >> 2;
  int P = 0;
  for (int i = 0; i < b; ++i) P += (lens[i] + 3) >> 2;
  const int nit = (lens[b] + 3) >> 2;
  offb = (P * NBLK) / TOT;
  cntb = ((P + nit) * NBLK) / TOT - offb;
}

// ---------------------------------------------------------------------------
// prep1: blocks 0..63  -> u-partials (4 Ua rows each, coalesced)
//        blocks 64..67 -> w-partials: w[d] = sum_e va[e]*Wa[e,d]
//        blocks 68..71 -> partition plan for ga_main (one entry per block k)
__global__ void ga_prep1(const float* __restrict__ Wa,
                         const float* __restrict__ Ua,
                         const float* __restrict__ va,
                         const int* __restrict__ lens,
                         float* __restrict__ ws) {
  const int tid = threadIdx.x, bx = blockIdx.x;
  if (bx < 64) {
    const int d0 = bx * 4;
    float a0 = 0.f, a1 = 0.f;
#pragma unroll
    for (int j = 0; j < 4; ++j) {
      const float vd = va[d0 + j];
      const float* row = Ua + (size_t)(d0 + j) * Cn;
      a0 += vd * row[tid];
      a1 += vd * row[tid + 256];
    }
    ws[WS_UPART + bx * Cn + tid] = a0;
    ws[WS_UPART + bx * Cn + tid + 256] = a1;
  } else if (bx < 68) {
    const int k = bx - 64;                  // rows [64k, 64k+64)
    float wacc = 0.f;
    for (int e = k * 64; e < k * 64 + 64; ++e)
      wacc += va[e] * Wa[(size_t)e * Dn + tid];   // coalesced across tid
    ws[WS_WPART + k * Dn + tid] = wacc;
  } else {
    const int k = (bx - 68) * 256 + tid;    // 0..NBLK-1
    int b, it0, it1;
    ga_partition(lens, k, b, it0, it1);
    ((int*)ws)[WS_PLAN + k] = b | (it0 << 5) | (it1 << 17);  // 5+12+12 bits
  }
}

// prep2: blocks 0,1 reduce u-partials -> u[512]; block 2 reduces w, then qv[b]
__global__ void ga_prep2(const float* __restrict__ input, float* __restrict__ ws) {
  const int tid = threadIdx.x, bx = blockIdx.x;
  if (bx < 2) {
    const int c = bx * 256 + tid;
    float s = 0.f;
#pragma unroll
    for (int i = 0; i < 64; ++i) s += ws[WS_UPART + i * Cn + c];
    ws[WS_U + c] = s;
  } else {
    __shared__ float wsh[Dn];
    wsh[tid] = ws[WS_WPART + tid] + ws[WS_WPART + 256 + tid]
             + ws[WS_WPART + 512 + tid] + ws[WS_WPART + 768 + tid];
    __syncthreads();
    const int b = tid >> 3, l8 = tid & 7;   // 8 threads per batch
    float p = 0.f;
#pragma unroll
    for (int j = 0; j < Dn / 8; ++j) {
      const int d = l8 + j * 8;
      p += input[b * Dn + d] * wsh[d];
    }
    p += __shfl_xor(p, 1);
    p += __shfl_xor(p, 2);
    p += __shfl_xor(p, 4);
    if (l8 == 0) ws[WS_QV + b] = p;
  }
}

// ---------------------------------------------------------------------------
// main: NBLK blocks, 4 waves each. Each wave runs TWO independent
// online-softmax streams (rows base+w and base+4+w) so 4 KiB of loads are in
// flight per wave and the dot/shfl/exp dependency chains interleave (2x ILP).
// __launch_bounds__(256,4): <=128 VGPR, no spills, 4 blocks/CU co-resident.
__global__ __launch_bounds__(256, 4) void ga_main(const float* __restrict__ context,
                                                  const int* __restrict__ lens,
                                                  float* __restrict__ ws) {
  const int k = blockIdx.x;
  const int plan = ((const int*)ws)[WS_PLAN + k];
  const int b   = plan & 31;
  const int it0 = (plan >> 5)  & 0xFFF;
  const int it1 = (plan >> 17) & 0xFFF;
  const int tid  = threadIdx.x;
  const int wave = tid >> 6;
  const int lane = tid & 63;
  const int len = lens[b];
  const float qv = ws[WS_QV + b];

  const float4* uv = (const float4*)(ws + WS_U);
  const float4 u0 = uv[lane];
  const float4 u1 = uv[64 + lane];

  float mA = -INFINITY, lA = 0.f, mB = -INFINITY, lB = 0.f;
  float4 aA0 = make_float4(0.f,0.f,0.f,0.f), aA1 = aA0, aB0 = aA0, aB1 = aA0;
  const float* cbase = context + (size_t)b * Sn * Cn;
  float* alout = ws + WS_ALIGN + (size_t)b * Sn;

  for (int it = it0; it < it1; it += 2) {
    const int sA = it * 4 + wave;
    const bool hasB = (it + 1) < it1;
    const int sB = hasB ? sA + 4 : sA;      // clamped addr stays in-bounds (L1 hit)
    const float4* pA = (const float4*)(cbase + (size_t)sA * Cn);
    const float4* pB = (const float4*)(cbase + (size_t)sB * Cn);
    const float4 fA0 = pA[lane];            // 4 KiB/wave in flight
    const float4 fA1 = pA[64 + lane];
    const float4 fB0 = pB[lane];
    const float4 fB1 = pB[64 + lane];

    float dA = fA0.x*u0.x + fA0.y*u0.y + fA0.z*u0.z + fA0.w*u0.w
             + fA1.x*u1.x + fA1.y*u1.y + fA1.z*u1.z + fA1.w*u1.w;
    float dB = fB0.x*u0.x + fB0.y*u0.y + fB0.z*u0.z + fB0.w*u0.w
             + fB1.x*u1.x + fB1.y*u1.y + fB1.z*u1.z + fB1.w*u1.w;
#pragma unroll
    for (int off = 32; off; off >>= 1) {    // two independent 6-chains, ILP 2x
      dA += __shfl_xor(dA, off);
      dB += __shfl_xor(dB, off);
    }

    if (sA < len) {
      const float al = qv + dA;
      if (lane == 0) alout[sA] = al;
      const float mn = fmaxf(mA, al);
      const float sc = __expf(mA - mn);     // mA=-inf first time -> sc=0, safe
      const float p  = __expf(al - mn);
      lA = lA * sc + p;
      aA0.x = aA0.x*sc + p*fA0.x;  aA0.y = aA0.y*sc + p*fA0.y;
      aA0.z = aA0.z*sc + p*fA0.z;  aA0.w = aA0.w*sc + p*fA0.w;
      aA1.x = aA1.x*sc + p*fA1.x;  aA1.y = aA1.y*sc + p*fA1.y;
      aA1.z = aA1.z*sc + p*fA1.z;  aA1.w = aA1.w*sc + p*fA1.w;
      mA = mn;
    }
    if (hasB && sB < len) {
      const float al = qv + dB;
      if (lane == 0) alout[sB] = al;
      const float mn = fmaxf(mB, al);
      const float sc = __expf(mB - mn);
      const float p  = __expf(al - mn);
      lB = lB * sc + p;
      aB0.x = aB0.x*sc + p*fB0.x;  aB0.y = aB0.y*sc + p*fB0.y;
      aB0.z = aB0.z*sc + p*fB0.z;  aB0.w = aB0.w*sc + p*fB0.w;
      aB1.x = aB1.x*sc + p*fB1.x;  aB1.y = aB1.y*sc + p*fB1.y;
      aB1.z = aB1.z*sc + p*fB1.z;  aB1.w = aB1.w*sc + p*fB1.w;
      mB = mn;
    }
  }

  // merge the two streams in-register
  float m = fmaxf(mA, mB);
  const float fSA = (mA == -INFINITY) ? 0.f : __expf(mA - m);
  const float fSB = (mB == -INFINITY) ? 0.f : __expf(mB - m);
  float l = lA * fSA + lB * fSB;
  float4 a0, a1;
  a0.x = aA0.x*fSA + aB0.x*fSB;  a0.y = aA0.y*fSA + aB0.y*fSB;
  a0.z = aA0.z*fSA + aB0.z*fSB;  a0.w = aA0.w*fSA + aB0.w*fSB;
  a1.x = aA1.x*fSA + aB1.x*fSB;  a1.y = aA1.y*fSA + aB1.y*fSB;
  a1.z = aA1.z*fSA + aB1.z*fSB;  a1.w = aA1.w*fSA + aB1.w*fSB;

  // combine the 4 waves' states -> one block partial at index k
  __shared__ float msh[4], lsh[4];
  __shared__ float accsh[4][Cn];
  if (lane == 0) msh[wave] = m;
  __syncthreads();
  const float M = fmaxf(fmaxf(msh[0], msh[1]), fmaxf(msh[2], msh[3]));
  const float f = (m == -INFINITY) ? 0.f : __expf(m - M);  // guard NaN
  float4* arow = (float4*)accsh[wave];
  arow[lane]      = make_float4(a0.x * f, a0.y * f, a0.z * f, a0.w * f);
  arow[64 + lane] = make_float4(a1.x * f, a1.y * f, a1.z * f, a1.w * f);
  if (lane == 0) lsh[wave] = l * f;
  __syncthreads();

  float* pacc = ws + WS_PACC + (size_t)k * Cn;
  for (int ch = tid; ch < Cn; ch += 256)
    pacc[ch] = accsh[0][ch] + accsh[1][ch] + accsh[2][ch] + accsh[3][ch];
  if (tid == 0) {
    ws[WS_PM + k] = M;
    ws[WS_PL + k] = lsh[0] + lsh[1] + lsh[2] + lsh[3];
  }
}

// ---------------------------------------------------------------------------
// finalize: 8 blocks per batch. cntb <= 63 => the (M, 1/L, wgt) reduce fits
// in wave 0. Each block handles 64 channels of attn_h and 1024 positions of
// align_vectors.
__global__ __launch_bounds__(256) void ga_finalize(const float* __restrict__ ws,
                                                   const int* __restrict__ lens,
                                                   float* __restrict__ out) {
  const int b = blockIdx.x >> 3, p = blockIdx.x & 7;
  const int tid = threadIdx.x;
  int offb, cntb;
  ga_batch_range(lens, b, offb, cntb);

  __shared__ float wgt[64];
  __shared__ float red[4][64];
  __shared__ float Msh, Lish;

  if (tid < 64) {
    const float mi = (tid < cntb) ? ws[WS_PM + offb + tid] : -INFINITY;
    float mm = mi;
#pragma unroll
    for (int off = 32; off; off >>= 1) mm = fmaxf(mm, __shfl_xor(mm, off));
    const float wi = (mi == -INFINITY) ? 0.f : __expf(mi - mm);
    wgt[tid] = wi;
    float li = (tid < cntb) ? ws[WS_PL + offb + tid] * wi : 0.f;
#pragma unroll
    for (int off = 32; off; off >>= 1) li += __shfl_xor(li, off);
    if (tid == 0) { Msh = mm; Lish = 1.f / li; }
  }
  __syncthreads();
  const float M = Msh, Li = Lish;

  // attn_h: this block covers channels [64p, 64p+64)
  {
    const int c = p * 64 + (tid & 63), g = tid >> 6;
    const float* pacc = ws + WS_PACC + (size_t)offb * Cn;
    float s = 0.f;
    for (int i = g; i < cntb; i += 4) s += wgt[i] * pacc[(size_t)i * Cn + c];
    red[g][tid & 63] = s;
    __syncthreads();
    if (tid < 64)
      out[b * Cn + p * 64 + tid] =
          (red[0][tid] + red[1][tid] + red[2][tid] + red[3][tid]) * Li;
  }

  // align_vectors: this block covers s in [1024p, 1024p+1024)
  {
    const int len = lens[b];
    const float* al = ws + WS_ALIGN + (size_t)b * Sn;
    float* ao = out + Bn * Cn + (size_t)b * Sn;
    const int s0 = p * 1024 + tid * 4;
    const float4 v = *(const float4*)(al + s0);  // s>=len lanes read stale ws,
    float4 o;                                    // discarded by the selects:
    o.x = (s0 + 0 < len) ? __expf(v.x - M) * Li : 0.f;
    o.y = (s0 + 1 < len) ? __expf(v.y - M) * Li : 0.f;
    o.z = (s0 + 2 < len) ? __expf(v.z - M) * Li : 0.f;
    o.w = (s0 + 3 < len) ? __expf(v.w - M) * Li : 0.f;
    *(float4*)(ao + s0) = o;
  }
}

// ---------------------------------------------------------------------------
extern "C" void kernel_launch(void* const* d_in, const int* in_sizes, int n_in,
                              void* d_out, int out_size, void* d_ws, size_t ws_size,
                              hipStream_t stream) {
  const float* input   = (const float*)d_in[0];
  const float* context = (const float*)d_in[1];
  const float* Wa      = (const float*)d_in[2];
  const float* Ua      = (const float*)d_in[3];
  const float* va      = (const float*)d_in[4];
  const int*   lens    = (const int*)d_in[5];
  float* out = (float*)d_out;
  float* ws  = (float*)d_ws;

  ga_prep1<<<72, 256, 0, stream>>>(Wa, Ua, va, lens, ws);
  ga_prep2<<<3, 256, 0, stream>>>(input, ws);
  ga_main<<<NBLK, 256, 0, stream>>>(context, lens, ws);
  ga_finalize<<<Bn * 8, 256, 0, stream>>>(ws, lens, out);
}